// Round 2
// baseline (2079.230 us; speedup 1.0000x reference)
//
#include <hip/hip_runtime.h>

namespace {
constexpr int kDim   = 256;
constexpr int kCodes = 8192;
constexpr int kRows  = 16384;   // 16 * 32 * 32
constexpr int kMBlk  = 64;
constexpr int kNBlk  = 64;
constexpr int kKC    = 32;
constexpr int kOutZq   = 16 * 256 * 32 * 32;  // 4194304
constexpr int kOutLoss = kOutZq;              // flat index of loss scalar
constexpr int kOutIdx  = kOutZq + 1;          // start of idx (as float)
}

// Pass 1: fused GEMM-argmin emulating the reference's f32 numerics.
// Reference computes d = fl32(fl32(||z||^2 + ||e||^2) - 2*dot) in f32.
// Since ||e||^2 (~1.3e-6) < half-ulp(||z||^2 ~ 256), it is absorbed:
// d = fl32(s - 2*dot). We replicate that quantized metric exactly
// (argmin is invariant to grid-multiple shifts of s, so any accurate
// f32 s works), with np.argmin's first-min (lowest index) tie-break.
__global__ __launch_bounds__(256) void vq_pass1(
    const float* __restrict__ z, const float* __restrict__ cb,
    int* __restrict__ cand) {
  __shared__ __align__(16) float As[kDim * kMBlk];  // As[d][r], 64 KB
  __shared__ __align__(16) float Bs[kKC * kNBlk];   // Bs[kk][c], 8 KB
  __shared__ float Ss[kMBlk];
  const int tid = threadIdx.x;
  const int m0  = blockIdx.x * kMBlk;

  // Stage A (z rows, transposed to [d][row]); coalesced over consecutive hw.
  {
    const int r  = tid & 63;
    const int d0 = tid >> 6;  // 0..3
    const int n  = m0 + r;
    const int b  = n >> 10;
    const int hw = n & 1023;
    const float* zp = z + ((size_t)b << 18) + hw;
    for (int j = 0; j < 64; ++j) {
      const int d = d0 + (j << 2);
      As[d * kMBlk + r] = zp[(size_t)d << 10];
    }
  }
  __syncthreads();

  // Per-row s = sum(z^2) in f32, 8-accumulator pairwise-ish order,
  // strictly non-contracted f32 ops.
  if (tid < kMBlk) {
    float r8[8];
#pragma unroll
    for (int j = 0; j < 8; ++j) {
      const float v = As[j * kMBlk + tid];
      r8[j] = __fmul_rn(v, v);
    }
    for (int d = 8; d < kDim; d += 8) {
#pragma unroll
      for (int j = 0; j < 8; ++j) {
        const float v = As[(d + j) * kMBlk + tid];
        r8[j] = __fadd_rn(r8[j], __fmul_rn(v, v));
      }
    }
    Ss[tid] = __fadd_rn(
        __fadd_rn(__fadd_rn(r8[0], r8[1]), __fadd_rn(r8[2], r8[3])),
        __fadd_rn(__fadd_rn(r8[4], r8[5]), __fadd_rn(r8[6], r8[7])));
  }
  __syncthreads();

  const int tx = tid & 15;
  const int ty = tid >> 4;
  float srow[4];
#pragma unroll
  for (int i = 0; i < 4; ++i) srow[i] = Ss[ty * 4 + i];

  float bd[4];
  int   bi[4];
#pragma unroll
  for (int i = 0; i < 4; ++i) { bd[i] = 3.4e38f; bi[i] = 0; }

  for (int n0 = 0; n0 < kCodes; n0 += kNBlk) {
    float acc[4][4];
#pragma unroll
    for (int i = 0; i < 4; ++i)
#pragma unroll
      for (int j = 0; j < 4; ++j) acc[i][j] = 0.f;

    for (int kc = 0; kc < kDim / kKC; ++kc) {
      __syncthreads();
      // Stage B chunk: 64 codes x 32 dims, transposed to [kk][code].
#pragma unroll
      for (int rep = 0; rep < 2; ++rep) {
        const int s  = tid + rep * 256;
        const int c  = s >> 3;
        const int fo = (s & 7) << 2;
        const float4 v = *reinterpret_cast<const float4*>(
            &cb[(size_t)(n0 + c) * kDim + kc * kKC + fo]);
        Bs[(fo + 0) * kNBlk + c] = v.x;
        Bs[(fo + 1) * kNBlk + c] = v.y;
        Bs[(fo + 2) * kNBlk + c] = v.z;
        Bs[(fo + 3) * kNBlk + c] = v.w;
      }
      __syncthreads();
#pragma unroll
      for (int kk = 0; kk < kKC; ++kk) {
        const float4 av = *reinterpret_cast<const float4*>(
            &As[(kc * kKC + kk) * kMBlk + ty * 4]);
        const float4 bv = *reinterpret_cast<const float4*>(
            &Bs[kk * kNBlk + tx * 4]);
        const float a[4] = {av.x, av.y, av.z, av.w};
        const float b[4] = {bv.x, bv.y, bv.z, bv.w};
#pragma unroll
        for (int i = 0; i < 4; ++i)
#pragma unroll
          for (int j = 0; j < 4; ++j) acc[i][j] = fmaf(a[i], b[j], acc[i][j]);
      }
    }
    // Quantized-metric argmin update for this 64-code tile.
    // 2*acc is exact (power of two); __fsub_rn gives fl32(s - 2*dot),
    // reproducing the reference's ulp(s)-grid quantization.
#pragma unroll
    for (int i = 0; i < 4; ++i) {
#pragma unroll
      for (int j = 0; j < 4; ++j) {
        const float dv = __fsub_rn(srow[i], 2.0f * acc[i][j]);
        if (dv < bd[i]) {  // strict: first (lowest) index wins ties
          bd[i] = dv;
          bi[i] = n0 + tx * 4 + j;
        }
      }
    }
  }

  // Cross-thread merge over the 16 tx threads sharing each row (reuse As).
  __syncthreads();
  float2* merge = reinterpret_cast<float2*>(As);  // [64 rows][16 tx]
#pragma unroll
  for (int i = 0; i < 4; ++i)
    merge[(ty * 4 + i) * 16 + tx] = make_float2(bd[i], __int_as_float(bi[i]));
  __syncthreads();
  if (tid < kMBlk) {
    float best = 3.4e38f;
    int   besti = 0x7fffffff;
    for (int t = 0; t < 16; ++t) {
      const float2 mv = merge[tid * 16 + t];
      const int ii = __float_as_int(mv.y);
      if (mv.x < best || (mv.x == best && ii < besti)) {
        best = mv.x;
        besti = ii;
      }
    }
    cand[m0 + tid] = besti;
  }
}

// Pass 2: gather z_q to [B,C,H,W], idx output, f64 loss partials.
__global__ __launch_bounds__(256) void vq_out(
    const float* __restrict__ z, const float* __restrict__ cb,
    const int* __restrict__ cand, float* __restrict__ out,
    double* __restrict__ bloss) {
  __shared__ double wsum[4];
  const int tid  = threadIdx.x;
  const int lane = tid & 63;
  const int wv   = tid >> 6;               // wave within block = row
  const int m    = blockIdx.x * 4 + wv;
  const int b    = m >> 10;
  const int hw   = m & 1023;
  const float* zr = z + ((size_t)b << 18) + hw;
  const int best = cand[m];
  const float* e = cb + (size_t)best * kDim;

  float* o0 = out + ((size_t)b << 18) + hw;
  double acc = 0;
#pragma unroll
  for (int j = 0; j < 4; ++j) {
    const int d = lane + j * 64;
    const float ev = e[d];
    const float zv = zr[(size_t)d << 10];
    o0[(size_t)d << 10] = ev;   // z_q_st == z_q numerically
    const double diff = (double)ev - (double)zv;
    acc += diff * diff;
  }
#pragma unroll
  for (int off = 32; off > 0; off >>= 1) acc += __shfl_xor(acc, off);
  if (lane == 0) {
    out[kOutIdx + m] = (float)best;
    wsum[wv] = acc;
  }
  __syncthreads();
  if (tid == 0) bloss[blockIdx.x] = wsum[0] + wsum[1] + wsum[2] + wsum[3];
}

// Pass 3: deterministic reduction of block partials -> loss scalar.
__global__ __launch_bounds__(256) void vq_final(
    const double* __restrict__ bloss, float* __restrict__ out) {
  __shared__ double sm[256];
  double s = 0;
  for (int i = threadIdx.x; i < kRows / 4; i += 256) s += bloss[i];
  sm[threadIdx.x] = s;
  __syncthreads();
  for (int st = 128; st > 0; st >>= 1) {
    if (threadIdx.x < st) sm[threadIdx.x] += sm[threadIdx.x + st];
    __syncthreads();
  }
  if (threadIdx.x == 0)
    out[kOutLoss] = (float)(1.25 * sm[0] / (double)kOutZq);
}

extern "C" void kernel_launch(void* const* d_in, const int* in_sizes, int n_in,
                              void* d_out, int out_size, void* d_ws, size_t ws_size,
                              hipStream_t stream) {
  const float* z  = (const float*)d_in[0];
  const float* cb = (const float*)d_in[1];
  float* out = (float*)d_out;
  int*    cand  = (int*)d_ws;                                    // 64 KB
  double* bloss = (double*)((char*)d_ws + kRows * sizeof(int));  // 32 KB

  vq_pass1<<<kRows / kMBlk, 256, 0, stream>>>(z, cb, cand);
  vq_out  <<<kRows / 4,     256, 0, stream>>>(z, cb, cand, out, bloss);
  vq_final<<<1,             256, 0, stream>>>(bloss, out);
}

// Round 3
// 1598.331 us; speedup vs baseline: 1.3009x; 1.3009x over previous
//
#include <hip/hip_runtime.h>

namespace {
constexpr int kDim   = 256;
constexpr int kCodes = 8192;
constexpr int kRows  = 16384;   // 16 * 32 * 32
constexpr int kOutZq   = 16 * 256 * 32 * 32;  // 4194304
constexpr int kOutLoss = kOutZq;
constexpr int kOutIdx  = kOutZq + 1;
constexpr int kSlices  = 8;
// fast-path ws layout (bytes)
constexpr size_t kOffCbT   = 0;                                   // 256*8192*4 = 8 MB
constexpr size_t kOffSrow  = (size_t)kDim * kCodes * 4;           // + 64 KB
constexpr size_t kOffPart  = kOffSrow + (size_t)kRows * 4;        // + 1 MB
constexpr size_t kOffBloss = kOffPart + (size_t)kRows * kSlices * 8;
constexpr size_t kWsNeed   = kOffBloss + (size_t)(kRows / 4) * 8;
}

// ---------------- fast path ----------------

// Transpose codebook [K=8192][D=256] -> cbT [D=256][K=8192] (LDS-tiled).
__global__ __launch_bounds__(256) void vq_tr(const float* __restrict__ cb,
                                             float* __restrict__ cbT) {
  __shared__ float t[64][65];
  const int k0 = blockIdx.x * 64;
  const int d0 = blockIdx.y * 64;
  const int tx = threadIdx.x & 15;   // float4 group
  const int r  = threadIdx.x >> 4;   // 0..15
  for (int rr = r; rr < 64; rr += 16) {
    const float4 v = *reinterpret_cast<const float4*>(
        &cb[(size_t)(k0 + rr) * kDim + d0 + tx * 4]);
    t[tx * 4 + 0][rr] = v.x; t[tx * 4 + 1][rr] = v.y;
    t[tx * 4 + 2][rr] = v.z; t[tx * 4 + 3][rr] = v.w;
  }
  __syncthreads();
  for (int rr = r; rr < 64; rr += 16) {
    float4 w;
    w.x = t[rr][tx * 4 + 0]; w.y = t[rr][tx * 4 + 1];
    w.z = t[rr][tx * 4 + 2]; w.w = t[rr][tx * 4 + 3];
    *reinterpret_cast<float4*>(&cbT[(size_t)(d0 + rr) * kCodes + k0 + tx * 4]) = w;
  }
}

// Per-row s = sum(z^2), EXACT same f32 op order as the validated R2 kernel.
__global__ __launch_bounds__(256) void vq_rows(const float* __restrict__ z,
                                               float* __restrict__ srow) {
  const int m  = blockIdx.x * 256 + threadIdx.x;
  const int b  = m >> 10, hw = m & 1023;
  const float* zp = z + ((size_t)b << 18) + hw;
  float r8[8];
#pragma unroll
  for (int j = 0; j < 8; ++j) {
    const float v = zp[(size_t)j << 10];
    r8[j] = __fmul_rn(v, v);
  }
  for (int d = 8; d < kDim; d += 8) {
#pragma unroll
    for (int j = 0; j < 8; ++j) {
      const float v = zp[(size_t)(d + j) << 10];
      r8[j] = __fadd_rn(r8[j], __fmul_rn(v, v));
    }
  }
  srow[m] = __fadd_rn(
      __fadd_rn(__fadd_rn(r8[0], r8[1]), __fadd_rn(r8[2], r8[3])),
      __fadd_rn(__fadd_rn(r8[4], r8[5]), __fadd_rn(r8[6], r8[7])));
}

// Zero-LDS fused GEMM-argmin. A = z (native [K][M] layout), B = cbT ([K][N]).
// 4 rows x 8 codes per thread; per kk: 3 float4 global loads + 32 fmaf.
// Dot fma chain is ascending-k sequential: bit-identical to the R2 kernel.
// Grid: (m-tile, slice): bid = mt*8 + s  -> slice s maps to XCD s (L2-resident
// 1 MB cbT slice under round-robin dispatch; perf-only assumption).
__global__ __launch_bounds__(256, 4) void vq_pass1f(
    const float* __restrict__ z, const float* __restrict__ cbT,
    const float* __restrict__ srow, float2* __restrict__ part) {
  const int s  = blockIdx.x & 7;
  const int mt = blockIdx.x >> 3;
  const int tx = threadIdx.x & 15;   // codes: 16 tx * 8 = 128 per tile
  const int ty = threadIdx.x >> 4;   // rows:  16 ty * 4 = 64
  const int m0 = mt * 64;
  const int b  = m0 >> 10;
  const int hw = (m0 & 1023) + ty * 4;
  const float* zp = z + ((size_t)b << 18) + hw;

  float sr[4];
#pragma unroll
  for (int i = 0; i < 4; ++i) sr[i] = srow[m0 + ty * 4 + i];

  float bd[4]; int bi[4];
#pragma unroll
  for (int i = 0; i < 4; ++i) { bd[i] = 3.4e38f; bi[i] = 0x7fffffff; }

  const int cbase = s * 1024 + tx * 8;
  for (int t = 0; t < 8; ++t) {
    const int n0 = cbase + t * 128;
    const float* bp = cbT + n0;
    float acc[4][8];
#pragma unroll
    for (int i = 0; i < 4; ++i)
#pragma unroll
      for (int j = 0; j < 8; ++j) acc[i][j] = 0.f;

#pragma unroll 4
    for (int kk = 0; kk < kDim; ++kk) {
      const float4 av = *reinterpret_cast<const float4*>(&zp[(size_t)kk << 10]);
      const float4 b0 = *reinterpret_cast<const float4*>(&bp[(size_t)kk * kCodes]);
      const float4 b1 = *reinterpret_cast<const float4*>(&bp[(size_t)kk * kCodes + 4]);
      const float a[4]  = {av.x, av.y, av.z, av.w};
      const float bb[8] = {b0.x, b0.y, b0.z, b0.w, b1.x, b1.y, b1.z, b1.w};
#pragma unroll
      for (int i = 0; i < 4; ++i)
#pragma unroll
        for (int j = 0; j < 8; ++j) acc[i][j] = fmaf(a[i], bb[j], acc[i][j]);
    }
    // Quantized metric fl32(s - 2*dot); strict < keeps lowest index
    // (within-thread candidate order is ascending).
#pragma unroll
    for (int i = 0; i < 4; ++i)
#pragma unroll
      for (int j = 0; j < 8; ++j) {
        const float dv = __fsub_rn(sr[i], 2.0f * acc[i][j]);
        if (dv < bd[i]) { bd[i] = dv; bi[i] = n0 + j; }
      }
  }

  // Cross-lane merge: the 16 tx lanes of a row group are consecutive lanes.
#pragma unroll
  for (int i = 0; i < 4; ++i) {
    float v = bd[i]; int ix = bi[i];
#pragma unroll
    for (int off = 1; off < 16; off <<= 1) {
      const float ov = __shfl_xor(v, off);
      const int   oi = __shfl_xor(ix, off);
      if (ov < v || (ov == v && oi < ix)) { v = ov; ix = oi; }
    }
    if (tx == 0)
      part[(size_t)(m0 + ty * 4 + i) * kSlices + s] =
          make_float2(v, __int_as_float(ix));
  }
}

// Merge slice partials, gather z_q, idx, f64 loss partials.
__global__ __launch_bounds__(256) void vq_outf(
    const float* __restrict__ z, const float* __restrict__ cb,
    const float2* __restrict__ part, float* __restrict__ out,
    double* __restrict__ bloss) {
  __shared__ double wsum[4];
  const int tid  = threadIdx.x;
  const int lane = tid & 63;
  const int wv   = tid >> 6;
  const int m    = blockIdx.x * 4 + wv;
  const int b    = m >> 10;
  const int hw   = m & 1023;

  float v = 3.4e38f; int ix = 0x7fffffff;
  if (lane < kSlices) {
    const float2 p = part[(size_t)m * kSlices + lane];
    v = p.x; ix = __float_as_int(p.y);
  }
#pragma unroll
  for (int off = 1; off < 8; off <<= 1) {
    const float ov = __shfl_xor(v, off);
    const int   oi = __shfl_xor(ix, off);
    if (ov < v || (ov == v && oi < ix)) { v = ov; ix = oi; }
  }
  const int best = __shfl(ix, 0);

  const float* zr = z + ((size_t)b << 18) + hw;
  const float* e  = cb + (size_t)best * kDim;
  float* o0 = out + ((size_t)b << 18) + hw;
  double acc = 0;
#pragma unroll
  for (int j = 0; j < 4; ++j) {
    const int d = lane + j * 64;
    const float ev = e[d];
    const float zv = zr[(size_t)d << 10];
    o0[(size_t)d << 10] = ev;
    const double diff = (double)ev - (double)zv;
    acc += diff * diff;
  }
#pragma unroll
  for (int off = 32; off > 0; off >>= 1) acc += __shfl_xor(acc, off);
  if (lane == 0) {
    out[kOutIdx + m] = (float)best;
    wsum[wv] = acc;
  }
  __syncthreads();
  if (tid == 0) bloss[blockIdx.x] = wsum[0] + wsum[1] + wsum[2] + wsum[3];
}

// Deterministic reduction of block partials -> loss scalar.
__global__ __launch_bounds__(256) void vq_final(
    const double* __restrict__ bloss, float* __restrict__ out) {
  __shared__ double sm[256];
  double s = 0;
  for (int i = threadIdx.x; i < kRows / 4; i += 256) s += bloss[i];
  sm[threadIdx.x] = s;
  __syncthreads();
  for (int st = 128; st > 0; st >>= 1) {
    if (threadIdx.x < st) sm[threadIdx.x] += sm[threadIdx.x + st];
    __syncthreads();
  }
  if (threadIdx.x == 0)
    out[kOutLoss] = (float)(1.25 * sm[0] / (double)kOutZq);
}

// ---------------- fallback path (verbatim Round-2, proven) ----------------

__global__ __launch_bounds__(256) void vq_pass1s(
    const float* __restrict__ z, const float* __restrict__ cb,
    int* __restrict__ cand) {
  __shared__ __align__(16) float As[kDim * 64];
  __shared__ __align__(16) float Bs[32 * 64];
  __shared__ float Ss[64];
  const int tid = threadIdx.x;
  const int m0  = blockIdx.x * 64;
  {
    const int r  = tid & 63;
    const int d0 = tid >> 6;
    const int n  = m0 + r;
    const int b  = n >> 10;
    const int hw = n & 1023;
    const float* zp = z + ((size_t)b << 18) + hw;
    for (int j = 0; j < 64; ++j) {
      const int d = d0 + (j << 2);
      As[d * 64 + r] = zp[(size_t)d << 10];
    }
  }
  __syncthreads();
  if (tid < 64) {
    float r8[8];
#pragma unroll
    for (int j = 0; j < 8; ++j) {
      const float v = As[j * 64 + tid];
      r8[j] = __fmul_rn(v, v);
    }
    for (int d = 8; d < kDim; d += 8) {
#pragma unroll
      for (int j = 0; j < 8; ++j) {
        const float v = As[(d + j) * 64 + tid];
        r8[j] = __fadd_rn(r8[j], __fmul_rn(v, v));
      }
    }
    Ss[tid] = __fadd_rn(
        __fadd_rn(__fadd_rn(r8[0], r8[1]), __fadd_rn(r8[2], r8[3])),
        __fadd_rn(__fadd_rn(r8[4], r8[5]), __fadd_rn(r8[6], r8[7])));
  }
  __syncthreads();
  const int tx = tid & 15;
  const int ty = tid >> 4;
  float srw[4];
#pragma unroll
  for (int i = 0; i < 4; ++i) srw[i] = Ss[ty * 4 + i];
  float bd[4]; int bi[4];
#pragma unroll
  for (int i = 0; i < 4; ++i) { bd[i] = 3.4e38f; bi[i] = 0; }
  for (int n0 = 0; n0 < kCodes; n0 += 64) {
    float acc[4][4];
#pragma unroll
    for (int i = 0; i < 4; ++i)
#pragma unroll
      for (int j = 0; j < 4; ++j) acc[i][j] = 0.f;
    for (int kc = 0; kc < kDim / 32; ++kc) {
      __syncthreads();
#pragma unroll
      for (int rep = 0; rep < 2; ++rep) {
        const int s  = tid + rep * 256;
        const int c  = s >> 3;
        const int fo = (s & 7) << 2;
        const float4 v = *reinterpret_cast<const float4*>(
            &cb[(size_t)(n0 + c) * kDim + kc * 32 + fo]);
        Bs[(fo + 0) * 64 + c] = v.x;
        Bs[(fo + 1) * 64 + c] = v.y;
        Bs[(fo + 2) * 64 + c] = v.z;
        Bs[(fo + 3) * 64 + c] = v.w;
      }
      __syncthreads();
#pragma unroll
      for (int kk = 0; kk < 32; ++kk) {
        const float4 av = *reinterpret_cast<const float4*>(
            &As[(kc * 32 + kk) * 64 + ty * 4]);
        const float4 bv = *reinterpret_cast<const float4*>(
            &Bs[kk * 64 + tx * 4]);
        const float a[4] = {av.x, av.y, av.z, av.w};
        const float b[4] = {bv.x, bv.y, bv.z, bv.w};
#pragma unroll
        for (int i = 0; i < 4; ++i)
#pragma unroll
          for (int j = 0; j < 4; ++j) acc[i][j] = fmaf(a[i], b[j], acc[i][j]);
      }
    }
#pragma unroll
    for (int i = 0; i < 4; ++i)
#pragma unroll
      for (int j = 0; j < 4; ++j) {
        const float dv = __fsub_rn(srw[i], 2.0f * acc[i][j]);
        if (dv < bd[i]) { bd[i] = dv; bi[i] = n0 + tx * 4 + j; }
      }
  }
  __syncthreads();
  float2* merge = reinterpret_cast<float2*>(As);
#pragma unroll
  for (int i = 0; i < 4; ++i)
    merge[(ty * 4 + i) * 16 + tx] = make_float2(bd[i], __int_as_float(bi[i]));
  __syncthreads();
  if (tid < 64) {
    float best = 3.4e38f;
    int   besti = 0x7fffffff;
    for (int t = 0; t < 16; ++t) {
      const float2 mv = merge[tid * 16 + t];
      const int ii = __float_as_int(mv.y);
      if (mv.x < best || (mv.x == best && ii < besti)) { best = mv.x; besti = ii; }
    }
    cand[m0 + tid] = besti;
  }
}

__global__ __launch_bounds__(256) void vq_outs(
    const float* __restrict__ z, const float* __restrict__ cb,
    const int* __restrict__ cand, float* __restrict__ out,
    double* __restrict__ bloss) {
  __shared__ double wsum[4];
  const int tid  = threadIdx.x;
  const int lane = tid & 63;
  const int wv   = tid >> 6;
  const int m    = blockIdx.x * 4 + wv;
  const int b    = m >> 10;
  const int hw   = m & 1023;
  const float* zr = z + ((size_t)b << 18) + hw;
  const int best = cand[m];
  const float* e = cb + (size_t)best * kDim;
  float* o0 = out + ((size_t)b << 18) + hw;
  double acc = 0;
#pragma unroll
  for (int j = 0; j < 4; ++j) {
    const int d = lane + j * 64;
    const float ev = e[d];
    const float zv = zr[(size_t)d << 10];
    o0[(size_t)d << 10] = ev;
    const double diff = (double)ev - (double)zv;
    acc += diff * diff;
  }
#pragma unroll
  for (int off = 32; off > 0; off >>= 1) acc += __shfl_xor(acc, off);
  if (lane == 0) {
    out[kOutIdx + m] = (float)best;
    wsum[wv] = acc;
  }
  __syncthreads();
  if (tid == 0) bloss[blockIdx.x] = wsum[0] + wsum[1] + wsum[2] + wsum[3];
}

extern "C" void kernel_launch(void* const* d_in, const int* in_sizes, int n_in,
                              void* d_out, int out_size, void* d_ws, size_t ws_size,
                              hipStream_t stream) {
  const float* z  = (const float*)d_in[0];
  const float* cb = (const float*)d_in[1];
  float* out = (float*)d_out;

  if (ws_size >= kWsNeed) {
    float*  cbT   = (float*)((char*)d_ws + kOffCbT);
    float*  srow  = (float*)((char*)d_ws + kOffSrow);
    float2* part  = (float2*)((char*)d_ws + kOffPart);
    double* bloss = (double*)((char*)d_ws + kOffBloss);
    vq_tr    <<<dim3(kCodes / 64, kDim / 64), 256, 0, stream>>>(cb, cbT);
    vq_rows  <<<kRows / 256, 256, 0, stream>>>(z, srow);
    vq_pass1f<<<(kRows / 64) * kSlices, 256, 0, stream>>>(z, cbT, srow, part);
    vq_outf  <<<kRows / 4, 256, 0, stream>>>(z, cb, part, out, bloss);
    vq_final <<<1, 256, 0, stream>>>(bloss, out);
  } else {
    int*    cand  = (int*)d_ws;                                    // 64 KB
    double* bloss = (double*)((char*)d_ws + kRows * sizeof(int));  // 32 KB
    vq_pass1s<<<kRows / 64, 256, 0, stream>>>(z, cb, cand);
    vq_outs  <<<kRows / 4,  256, 0, stream>>>(z, cb, cand, out, bloss);
    vq_final <<<1, 256, 0, stream>>>(bloss, out);
  }
}

// Round 4
// 470.626 us; speedup vs baseline: 4.4180x; 3.3962x over previous
//
#include <hip/hip_runtime.h>

typedef short  bhalf8  __attribute__((ext_vector_type(8)));
typedef float  floatx4 __attribute__((ext_vector_type(4)));
typedef unsigned long long u64;

namespace {
constexpr int kDim   = 256;
constexpr int kCodes = 8192;
constexpr int kRows  = 16384;   // 16 * 32 * 32
constexpr int kOutZq   = 16 * 256 * 32 * 32;  // 4194304
constexpr int kOutLoss = kOutZq;
constexpr int kOutIdx  = kOutZq + 1;
constexpr int kNT = kCodes / 128;             // 64 N-tiles
constexpr unsigned kCap = 262144;
constexpr float kMargin = 4e-5f;  // half-bin 1.53e-5 + ~16 sigma approx err

// ws layout (bytes)
constexpr size_t kOffZb    = 0;                                  // 8 MB bf16 z, K-blocked
constexpr size_t kOffCbb   = kOffZb  + (size_t)kRows * kDim * 2; // 4 MB bf16 cb, K-blocked
constexpr size_t kOffSrow  = kOffCbb + (size_t)kCodes * kDim * 2;
constexpr size_t kOffRmax  = kOffSrow + (size_t)kRows * 4;
constexpr size_t kOffRmaxP = kOffRmax + (size_t)kRows * 4;       // [64][16384] f32
constexpr size_t kOffPack  = kOffRmaxP + (size_t)kNT * kRows * 4;
constexpr size_t kOffList  = kOffPack + (size_t)kRows * 8;
constexpr size_t kOffCnt   = kOffList + (size_t)kCap * 8;
constexpr size_t kOffBloss = kOffCnt + 256;
constexpr size_t kWsNeed   = kOffBloss + (size_t)(kRows / 4) * 8;
}

__device__ inline unsigned short f2bf(float f) {  // RNE f32 -> bf16
  unsigned u = __float_as_uint(f);
  u += 0x7fffu + ((u >> 16) & 1u);
  return (unsigned short)(u >> 16);
}

// z [b][d][hw] f32 -> zbK[kb=8][m=16384][kk=32] bf16 (K-blocked rows for staging).
__global__ __launch_bounds__(256) void vq_convz(const float* __restrict__ z,
                                                unsigned short* __restrict__ zbK) {
  const int m  = blockIdx.x * 256 + threadIdx.x;
  const int b  = m >> 10, hw = m & 1023;
  const float* zp = z + ((size_t)b << 18) + hw;
  for (int kb = 0; kb < 8; ++kb) {
    unsigned short tmp[32];
#pragma unroll
    for (int kk = 0; kk < 32; ++kk)
      tmp[kk] = f2bf(zp[(size_t)(kb * 32 + kk) << 10]);
#pragma unroll
    for (int q = 0; q < 4; ++q) {
      bhalf8 v;
#pragma unroll
      for (int j = 0; j < 8; ++j) v[j] = (short)tmp[q * 8 + j];
      *reinterpret_cast<bhalf8*>(
          &zbK[((size_t)(kb * kRows + m)) * 32 + q * 8]) = v;
    }
  }
}

// cb [n][d] f32 -> cbbK[kb=8][n=8192][kk=32] bf16.
__global__ __launch_bounds__(256) void vq_convcb(const float* __restrict__ cb,
                                                 unsigned short* __restrict__ cbbK) {
  const int n0 = blockIdx.x * 64;
  const int kq = threadIdx.x & 63;   // float4 index over k
  const int ns = threadIdx.x >> 6;
  const int kb = kq >> 3;
#pragma unroll
  for (int nn = 0; nn < 16; ++nn) {
    const int n = n0 + ns * 16 + nn;
    const float4 v = *reinterpret_cast<const float4*>(&cb[(size_t)n * kDim + kq * 4]);
    const unsigned w0 = (unsigned)f2bf(v.x) | ((unsigned)f2bf(v.y) << 16);
    const unsigned w1 = (unsigned)f2bf(v.z) | ((unsigned)f2bf(v.w) << 16);
    uint2* dst = reinterpret_cast<uint2*>(
        &cbbK[((size_t)(kb * kCodes + n)) * 32 + (kq & 7) * 4]);
    *dst = make_uint2(w0, w1);
  }
}

// Per-row s = sum(z^2), EXACT same f32 op order as the validated R2 kernel.
// Also inits pack[] and the append counter.
__global__ __launch_bounds__(256) void vq_rows(const float* __restrict__ z,
                                               float* __restrict__ srow,
                                               u64* __restrict__ pack,
                                               unsigned* __restrict__ cnt) {
  const int m  = blockIdx.x * 256 + threadIdx.x;
  const int b  = m >> 10, hw = m & 1023;
  const float* zp = z + ((size_t)b << 18) + hw;
  float r8[8];
#pragma unroll
  for (int j = 0; j < 8; ++j) {
    const float v = zp[(size_t)j << 10];
    r8[j] = __fmul_rn(v, v);
  }
  for (int d = 8; d < kDim; d += 8) {
#pragma unroll
    for (int j = 0; j < 8; ++j) {
      const float v = zp[(size_t)(d + j) << 10];
      r8[j] = __fadd_rn(r8[j], __fmul_rn(v, v));
    }
  }
  srow[m] = __fadd_rn(
      __fadd_rn(__fadd_rn(r8[0], r8[1]), __fadd_rn(r8[2], r8[3])),
      __fadd_rn(__fadd_rn(r8[4], r8[5]), __fadd_rn(r8[6], r8[7])));
  pack[m] = ~0ull;
  if (m == 0) *cnt = 0u;
}

// bf16 MFMA GEMM, 128x128 tile, BK=32, 4 waves (each: 32 rows x 128 cols).
// PHASE 0: per-row approx max -> rowmaxp[nt][row].
// PHASE 1: append (row,code) with score > rowmax[row]-margin to list.
template <int PHASE>
__global__ __launch_bounds__(256) void vq_gemm(
    const unsigned short* __restrict__ zbK,
    const unsigned short* __restrict__ cbbK,
    const float* __restrict__ rowmax, float* __restrict__ rowmaxp,
    u64* __restrict__ list, unsigned* __restrict__ cnt) {
  __shared__ short At[128 * 40];   // [row][k] pad->40 (conflict-free b128)
  __shared__ short Bt[128 * 40];   // [col][k]
  __shared__ float thr[128];
  const int tid  = threadIdx.x;
  const int nt   = blockIdx.x & (kNT - 1);
  const int mt   = blockIdx.x >> 6;
  const int m0   = mt * 128, n0 = nt * 128;
  const int w    = tid >> 6, lane = tid & 63;
  const int r16  = lane & 15, kg = lane >> 4;

  if (PHASE == 1 && tid < 128) thr[tid] = rowmax[m0 + tid] - kMargin;

  floatx4 acc[2][8];
#pragma unroll
  for (int i = 0; i < 2; ++i)
#pragma unroll
    for (int j = 0; j < 8; ++j) acc[i][j] = floatx4{0.f, 0.f, 0.f, 0.f};

  const int sr = tid >> 1;       // staged row/col 0..127
  const int sh = tid & 1;        // 16-bf16 half of the 32-k slice

  for (int kb = 0; kb < 8; ++kb) {
    __syncthreads();
    {  // stage A (z rows) and B (codes), fully coalesced 16B loads
      const unsigned short* za =
          zbK + ((size_t)(kb * kRows + m0 + sr)) * 32 + sh * 16;
      const unsigned short* ba =
          cbbK + ((size_t)(kb * kCodes + n0 + sr)) * 32 + sh * 16;
      const bhalf8 a0 = *reinterpret_cast<const bhalf8*>(za);
      const bhalf8 a1 = *reinterpret_cast<const bhalf8*>(za + 8);
      const bhalf8 b0 = *reinterpret_cast<const bhalf8*>(ba);
      const bhalf8 b1 = *reinterpret_cast<const bhalf8*>(ba + 8);
      *reinterpret_cast<bhalf8*>(&At[sr * 40 + sh * 16]) = a0;
      *reinterpret_cast<bhalf8*>(&At[sr * 40 + sh * 16 + 8]) = a1;
      *reinterpret_cast<bhalf8*>(&Bt[sr * 40 + sh * 16]) = b0;
      *reinterpret_cast<bhalf8*>(&Bt[sr * 40 + sh * 16 + 8]) = b1;
    }
    __syncthreads();
    bhalf8 af[2], bf[8];
#pragma unroll
    for (int mi = 0; mi < 2; ++mi)
      af[mi] = *reinterpret_cast<const bhalf8*>(
          &At[(w * 32 + mi * 16 + r16) * 40 + kg * 8]);
#pragma unroll
    for (int ni = 0; ni < 8; ++ni)
      bf[ni] = *reinterpret_cast<const bhalf8*>(
          &Bt[(ni * 16 + r16) * 40 + kg * 8]);
#pragma unroll
    for (int mi = 0; mi < 2; ++mi)
#pragma unroll
      for (int ni = 0; ni < 8; ++ni)
        acc[mi][ni] = __builtin_amdgcn_mfma_f32_16x16x32_bf16(
            af[mi], bf[ni], acc[mi][ni], 0, 0, 0);
  }

  // C frag mapping (guide-verified): col = lane&15, row = (lane>>4)*4 + reg.
  if (PHASE == 0) {
#pragma unroll
    for (int mi = 0; mi < 2; ++mi)
#pragma unroll
      for (int reg = 0; reg < 4; ++reg) {
        float v = acc[mi][0][reg];
#pragma unroll
        for (int ni = 1; ni < 8; ++ni) v = fmaxf(v, acc[mi][ni][reg]);
#pragma unroll
        for (int off = 1; off < 16; off <<= 1) v = fmaxf(v, __shfl_xor(v, off));
        if (r16 == 0)
          rowmaxp[(size_t)nt * kRows + m0 + w * 32 + mi * 16 + kg * 4 + reg] = v;
      }
  } else {
#pragma unroll
    for (int mi = 0; mi < 2; ++mi)
#pragma unroll
      for (int reg = 0; reg < 4; ++reg) {
        const int rl = w * 32 + mi * 16 + kg * 4 + reg;
        const float t = thr[rl];
#pragma unroll
        for (int ni = 0; ni < 8; ++ni) {
          if (acc[mi][ni][reg] > t) {
            const unsigned slot = atomicAdd(cnt, 1u);
            if (slot < kCap)
              list[slot] = ((u64)(unsigned)(m0 + rl) << 32) |
                           (unsigned)(n0 + ni * 16 + r16);
          }
        }
      }
  }
}

// rowmax[m] = max over 64 N-tiles.
__global__ __launch_bounds__(256) void vq_rmax(const float* __restrict__ rowmaxp,
                                               float* __restrict__ rowmax) {
  const int m = blockIdx.x * 256 + threadIdx.x;
  float v = rowmaxp[m];
  for (int s = 1; s < kNT; ++s) v = fmaxf(v, rowmaxp[(size_t)s * kRows + m]);
  rowmax[m] = v;
}

// Exact f32 rescore (bit-identical to R2 numerics): sequential ascending-k
// fmaf chain, dv = fl32(s - 2*dot); lex-min (dv, idx) via u64 atomicMin.
__global__ __launch_bounds__(256) void vq_rescore(
    const float* __restrict__ z, const float* __restrict__ cb,
    const float* __restrict__ srow, const u64* __restrict__ list,
    const unsigned* __restrict__ cnt, u64* __restrict__ pack) {
  const unsigned total = min(*cnt, kCap);
  for (unsigned i = blockIdx.x * 256 + threadIdx.x; i < total;
       i += gridDim.x * 256) {
    const u64 e = list[i];
    const int m = (int)(e >> 32);
    const int code = (int)(e & 0xffffffffu);
    const int b = m >> 10, hw = m & 1023;
    const float* zr = z + ((size_t)b << 18) + hw;
    const float* er = cb + (size_t)code * kDim;
    float d = 0.f;
    for (int k = 0; k < kDim; ++k)
      d = fmaf(zr[(size_t)k << 10], er[k], d);
    const float dv = __fsub_rn(srow[m], 2.0f * d);
    const u64 p = ((u64)__float_as_uint(dv) << 32) | (unsigned)code;
    atomicMin(pack + m, p);
  }
}

// Gather z_q to [B,C,H,W], idx output, f64 loss partials.
__global__ __launch_bounds__(256) void vq_out2(
    const float* __restrict__ z, const float* __restrict__ cb,
    const u64* __restrict__ pack, float* __restrict__ out,
    double* __restrict__ bloss) {
  __shared__ double wsum[4];
  const int tid  = threadIdx.x;
  const int lane = tid & 63;
  const int wv   = tid >> 6;
  const int m    = blockIdx.x * 4 + wv;
  const int b    = m >> 10;
  const int hw   = m & 1023;
  const u64 p = pack[m];
  const int best = (p == ~0ull) ? 0 : (int)(p & 0x7fffffffu);  // OOB guard
  const float* zr = z + ((size_t)b << 18) + hw;
  const float* e  = cb + (size_t)best * kDim;
  float* o0 = out + ((size_t)b << 18) + hw;
  double acc = 0;
#pragma unroll
  for (int j = 0; j < 4; ++j) {
    const int d = lane + j * 64;
    const float ev = e[d];
    const float zv = zr[(size_t)d << 10];
    o0[(size_t)d << 10] = ev;
    const double diff = (double)ev - (double)zv;
    acc += diff * diff;
  }
#pragma unroll
  for (int off = 32; off > 0; off >>= 1) acc += __shfl_xor(acc, off);
  if (lane == 0) {
    out[kOutIdx + m] = (float)best;
    wsum[wv] = acc;
  }
  __syncthreads();
  if (tid == 0) bloss[blockIdx.x] = wsum[0] + wsum[1] + wsum[2] + wsum[3];
}

__global__ __launch_bounds__(256) void vq_final(
    const double* __restrict__ bloss, float* __restrict__ out) {
  __shared__ double sm[256];
  double s = 0;
  for (int i = threadIdx.x; i < kRows / 4; i += 256) s += bloss[i];
  sm[threadIdx.x] = s;
  __syncthreads();
  for (int st = 128; st > 0; st >>= 1) {
    if (threadIdx.x < st) sm[threadIdx.x] += sm[threadIdx.x + st];
    __syncthreads();
  }
  if (threadIdx.x == 0)
    out[kOutLoss] = (float)(1.25 * sm[0] / (double)kOutZq);
}

// ---------------- fallback path (verbatim Round-2, proven) ----------------

__global__ __launch_bounds__(256) void vq_pass1s(
    const float* __restrict__ z, const float* __restrict__ cb,
    int* __restrict__ cand) {
  __shared__ __align__(16) float As[kDim * 64];
  __shared__ __align__(16) float Bs[32 * 64];
  __shared__ float Ss[64];
  const int tid = threadIdx.x;
  const int m0  = blockIdx.x * 64;
  {
    const int r  = tid & 63;
    const int d0 = tid >> 6;
    const int n  = m0 + r;
    const int b  = n >> 10;
    const int hw = n & 1023;
    const float* zp = z + ((size_t)b << 18) + hw;
    for (int j = 0; j < 64; ++j) {
      const int d = d0 + (j << 2);
      As[d * 64 + r] = zp[(size_t)d << 10];
    }
  }
  __syncthreads();
  if (tid < 64) {
    float r8[8];
#pragma unroll
    for (int j = 0; j < 8; ++j) {
      const float v = As[j * 64 + tid];
      r8[j] = __fmul_rn(v, v);
    }
    for (int d = 8; d < kDim; d += 8) {
#pragma unroll
      for (int j = 0; j < 8; ++j) {
        const float v = As[(d + j) * 64 + tid];
        r8[j] = __fadd_rn(r8[j], __fmul_rn(v, v));
      }
    }
    Ss[tid] = __fadd_rn(
        __fadd_rn(__fadd_rn(r8[0], r8[1]), __fadd_rn(r8[2], r8[3])),
        __fadd_rn(__fadd_rn(r8[4], r8[5]), __fadd_rn(r8[6], r8[7])));
  }
  __syncthreads();
  const int tx = tid & 15;
  const int ty = tid >> 4;
  float srw[4];
#pragma unroll
  for (int i = 0; i < 4; ++i) srw[i] = Ss[ty * 4 + i];
  float bd[4]; int bi[4];
#pragma unroll
  for (int i = 0; i < 4; ++i) { bd[i] = 3.4e38f; bi[i] = 0; }
  for (int n0 = 0; n0 < kCodes; n0 += 64) {
    float acc[4][4];
#pragma unroll
    for (int i = 0; i < 4; ++i)
#pragma unroll
      for (int j = 0; j < 4; ++j) acc[i][j] = 0.f;
    for (int kc = 0; kc < kDim / 32; ++kc) {
      __syncthreads();
#pragma unroll
      for (int rep = 0; rep < 2; ++rep) {
        const int s  = tid + rep * 256;
        const int c  = s >> 3;
        const int fo = (s & 7) << 2;
        const float4 v = *reinterpret_cast<const float4*>(
            &cb[(size_t)(n0 + c) * kDim + kc * 32 + fo]);
        Bs[(fo + 0) * 64 + c] = v.x;
        Bs[(fo + 1) * 64 + c] = v.y;
        Bs[(fo + 2) * 64 + c] = v.z;
        Bs[(fo + 3) * 64 + c] = v.w;
      }
      __syncthreads();
#pragma unroll
      for (int kk = 0; kk < 32; ++kk) {
        const float4 av = *reinterpret_cast<const float4*>(
            &As[(kc * 32 + kk) * 64 + ty * 4]);
        const float4 bv = *reinterpret_cast<const float4*>(
            &Bs[kk * 64 + tx * 4]);
        const float a[4] = {av.x, av.y, av.z, av.w};
        const float b[4] = {bv.x, bv.y, bv.z, bv.w};
#pragma unroll
        for (int i = 0; i < 4; ++i)
#pragma unroll
          for (int j = 0; j < 4; ++j) acc[i][j] = fmaf(a[i], b[j], acc[i][j]);
      }
    }
#pragma unroll
    for (int i = 0; i < 4; ++i)
#pragma unroll
      for (int j = 0; j < 4; ++j) {
        const float dv = __fsub_rn(srw[i], 2.0f * acc[i][j]);
        if (dv < bd[i]) { bd[i] = dv; bi[i] = n0 + tx * 4 + j; }
      }
  }
  __syncthreads();
  float2* merge = reinterpret_cast<float2*>(As);
#pragma unroll
  for (int i = 0; i < 4; ++i)
    merge[(ty * 4 + i) * 16 + tx] = make_float2(bd[i], __int_as_float(bi[i]));
  __syncthreads();
  if (tid < 64) {
    float best = 3.4e38f;
    int   besti = 0x7fffffff;
    for (int t = 0; t < 16; ++t) {
      const float2 mv = merge[tid * 16 + t];
      const int ii = __float_as_int(mv.y);
      if (mv.x < best || (mv.x == best && ii < besti)) { best = mv.x; besti = ii; }
    }
    cand[m0 + tid] = besti;
  }
}

__global__ __launch_bounds__(256) void vq_outs(
    const float* __restrict__ z, const float* __restrict__ cb,
    const int* __restrict__ cand, float* __restrict__ out,
    double* __restrict__ bloss) {
  __shared__ double wsum[4];
  const int tid  = threadIdx.x;
  const int lane = tid & 63;
  const int wv   = tid >> 6;
  const int m    = blockIdx.x * 4 + wv;
  const int b    = m >> 10;
  const int hw   = m & 1023;
  const float* zr = z + ((size_t)b << 18) + hw;
  const int best = cand[m];
  const float* e = cb + (size_t)best * kDim;
  float* o0 = out + ((size_t)b << 18) + hw;
  double acc = 0;
#pragma unroll
  for (int j = 0; j < 4; ++j) {
    const int d = lane + j * 64;
    const float ev = e[d];
    const float zv = zr[(size_t)d << 10];
    o0[(size_t)d << 10] = ev;
    const double diff = (double)ev - (double)zv;
    acc += diff * diff;
  }
#pragma unroll
  for (int off = 32; off > 0; off >>= 1) acc += __shfl_xor(acc, off);
  if (lane == 0) {
    out[kOutIdx + m] = (float)best;
    wsum[wv] = acc;
  }
  __syncthreads();
  if (tid == 0) bloss[blockIdx.x] = wsum[0] + wsum[1] + wsum[2] + wsum[3];
}

extern "C" void kernel_launch(void* const* d_in, const int* in_sizes, int n_in,
                              void* d_out, int out_size, void* d_ws, size_t ws_size,
                              hipStream_t stream) {
  const float* z  = (const float*)d_in[0];
  const float* cb = (const float*)d_in[1];
  float* out = (float*)d_out;

  if (ws_size >= kWsNeed) {
    unsigned short* zbK  = (unsigned short*)((char*)d_ws + kOffZb);
    unsigned short* cbbK = (unsigned short*)((char*)d_ws + kOffCbb);
    float* srow    = (float*)((char*)d_ws + kOffSrow);
    float* rowmax  = (float*)((char*)d_ws + kOffRmax);
    float* rowmaxp = (float*)((char*)d_ws + kOffRmaxP);
    u64*   pack    = (u64*)((char*)d_ws + kOffPack);
    u64*   list    = (u64*)((char*)d_ws + kOffList);
    unsigned* cnt  = (unsigned*)((char*)d_ws + kOffCnt);
    double* bloss  = (double*)((char*)d_ws + kOffBloss);

    vq_convz  <<<kRows / 256, 256, 0, stream>>>(z, zbK);
    vq_convcb <<<kCodes / 64, 256, 0, stream>>>(cb, cbbK);
    vq_rows   <<<kRows / 256, 256, 0, stream>>>(z, srow, pack, cnt);
    vq_gemm<0><<<(kRows / 128) * kNT, 256, 0, stream>>>(zbK, cbbK, rowmax,
                                                        rowmaxp, list, cnt);
    vq_rmax   <<<kRows / 256, 256, 0, stream>>>(rowmaxp, rowmax);
    vq_gemm<1><<<(kRows / 128) * kNT, 256, 0, stream>>>(zbK, cbbK, rowmax,
                                                        rowmaxp, list, cnt);
    vq_rescore<<<128, 256, 0, stream>>>(z, cb, srow, list, cnt, pack);
    vq_out2   <<<kRows / 4, 256, 0, stream>>>(z, cb, pack, out, bloss);
    vq_final  <<<1, 256, 0, stream>>>(bloss, out);
  } else {
    int*    cand  = (int*)d_ws;
    double* bloss = (double*)((char*)d_ws + kRows * sizeof(int));
    vq_pass1s<<<kRows / 64, 256, 0, stream>>>(z, cb, cand);
    vq_outs  <<<kRows / 4,  256, 0, stream>>>(z, cb, cand, out, bloss);
    vq_final <<<1, 256, 0, stream>>>(bloss, out);
  }
}

// Round 5
// 450.955 us; speedup vs baseline: 4.6107x; 1.0436x over previous
//
#include <hip/hip_runtime.h>

typedef short  bhalf8  __attribute__((ext_vector_type(8)));
typedef float  floatx4 __attribute__((ext_vector_type(4)));
typedef unsigned long long u64;

namespace {
constexpr int kDim   = 256;
constexpr int kCodes = 8192;
constexpr int kRows  = 16384;   // 16 * 32 * 32
constexpr int kOutZq   = 16 * 256 * 32 * 32;  // 4194304
constexpr int kOutLoss = kOutZq;
constexpr int kOutIdx  = kOutZq + 1;
constexpr int kNT = kCodes / 128;             // 64 N-tiles
constexpr unsigned kCap = 262144;
constexpr float kMargin = 4e-5f;  // half-bin 1.53e-5 + ~16 sigma approx err

// ws layout (bytes)
constexpr size_t kOffZf    = 0;                                  // 8 MB bf16 z, fragment order
constexpr size_t kOffCbf   = kOffZf  + (size_t)kRows * kDim * 2; // 4 MB bf16 cb, fragment order
constexpr size_t kOffSrow  = kOffCbf + (size_t)kCodes * kDim * 2;
constexpr size_t kOffRmax  = kOffSrow + (size_t)kRows * 4;
constexpr size_t kOffRmaxP = kOffRmax + (size_t)kRows * 4;       // [64][16384] f32
constexpr size_t kOffPack  = kOffRmaxP + (size_t)kNT * kRows * 4;
constexpr size_t kOffList  = kOffPack + (size_t)kRows * 8;
constexpr size_t kOffCnt   = kOffList + (size_t)kCap * 8;
constexpr size_t kOffBloss = kOffCnt + 256;
constexpr size_t kWsNeed   = kOffBloss + (size_t)(kRows / 4) * 8;
}

__device__ inline unsigned short f2bf(float f) {  // RNE f32 -> bf16
  unsigned u = __float_as_uint(f);
  u += 0x7fffu + ((u >> 16) & 1u);
  return (unsigned short)(u >> 16);
}

// async global->LDS, 16B per lane; lds base must be wave-uniform.
__device__ inline void gload_lds16(const void* g, void* l) {
  __builtin_amdgcn_global_load_lds(
      (const __attribute__((address_space(1))) unsigned int*)(g),
      (__attribute__((address_space(3))) unsigned int*)(l), 16, 0, 0);
}

// z [b][d][hw] f32 -> zF fragment order [kb=8][rt=1024][lane=64][8] bf16.
// MFMA 16x16x32 A-frag: lane holds row (lane&15), k = kb*32+(lane>>4)*8 ..+8.
__global__ __launch_bounds__(256) void vq_convz(const float* __restrict__ z,
                                                unsigned short* __restrict__ zF) {
  const int t    = blockIdx.x * 256 + threadIdx.x;  // 524288 entries
  const int kb   = t >> 16;
  const int rt   = (t >> 6) & 1023;
  const int lane = t & 63;
  const int m  = rt * 16 + (lane & 15);
  const int k0 = kb * 32 + (lane >> 4) * 8;
  const int b  = m >> 10, hw = m & 1023;
  const float* zp = z + ((size_t)b << 18) + hw;
  bhalf8 v;
#pragma unroll
  for (int j = 0; j < 8; ++j)
    v[j] = (short)f2bf(zp[(size_t)(k0 + j) << 10]);
  *reinterpret_cast<bhalf8*>(&zF[(size_t)t << 3]) = v;
}

// cb [n][d] f32 -> cbF fragment order [kb=8][ct=512][lane=64][8] bf16.
__global__ __launch_bounds__(256) void vq_convcb(const float* __restrict__ cb,
                                                 unsigned short* __restrict__ cbF) {
  const int t    = blockIdx.x * 256 + threadIdx.x;  // 262144 entries
  const int kb   = t >> 15;
  const int ct   = (t >> 6) & 511;
  const int lane = t & 63;
  const int col = ct * 16 + (lane & 15);
  const int k0  = kb * 32 + (lane >> 4) * 8;
  const float4 a = *reinterpret_cast<const float4*>(&cb[(size_t)col * kDim + k0]);
  const float4 c = *reinterpret_cast<const float4*>(&cb[(size_t)col * kDim + k0 + 4]);
  bhalf8 v;
  v[0] = (short)f2bf(a.x); v[1] = (short)f2bf(a.y);
  v[2] = (short)f2bf(a.z); v[3] = (short)f2bf(a.w);
  v[4] = (short)f2bf(c.x); v[5] = (short)f2bf(c.y);
  v[6] = (short)f2bf(c.z); v[7] = (short)f2bf(c.w);
  *reinterpret_cast<bhalf8*>(&cbF[(size_t)t << 3]) = v;
}

// Per-row s = sum(z^2), EXACT same f32 op order as the validated R2 kernel.
__global__ __launch_bounds__(256) void vq_rows(const float* __restrict__ z,
                                               float* __restrict__ srow,
                                               u64* __restrict__ pack,
                                               unsigned* __restrict__ cnt) {
  const int m  = blockIdx.x * 256 + threadIdx.x;
  const int b  = m >> 10, hw = m & 1023;
  const float* zp = z + ((size_t)b << 18) + hw;
  float r8[8];
#pragma unroll
  for (int j = 0; j < 8; ++j) {
    const float v = zp[(size_t)j << 10];
    r8[j] = __fmul_rn(v, v);
  }
  for (int d = 8; d < kDim; d += 8) {
#pragma unroll
    for (int j = 0; j < 8; ++j) {
      const float v = zp[(size_t)(d + j) << 10];
      r8[j] = __fadd_rn(r8[j], __fmul_rn(v, v));
    }
  }
  srow[m] = __fadd_rn(
      __fadd_rn(__fadd_rn(r8[0], r8[1]), __fadd_rn(r8[2], r8[3])),
      __fadd_rn(__fadd_rn(r8[4], r8[5]), __fadd_rn(r8[6], r8[7])));
  pack[m] = ~0ull;
  if (m == 0) *cnt = 0u;
}

// bf16 MFMA GEMM, block = 256 rows x 128 cols, 4 waves (each 64 rows x 128).
// A-fragments direct from zF (global, no LDS). B double-buffered in LDS via
// global_load_lds. PHASE 0: per-row approx max. PHASE 1: margin filter+append.
template <int PHASE>
__global__ __launch_bounds__(256, 2) void vq_gemm(
    const unsigned short* __restrict__ zF,
    const unsigned short* __restrict__ cbF,
    const float* __restrict__ rowmax, float* __restrict__ rowmaxp,
    u64* __restrict__ list, unsigned* __restrict__ cnt) {
  __shared__ __align__(16) unsigned short Bs[2][4096];  // 8 KB each
  const int tid  = threadIdx.x;
  const int mt   = blockIdx.x & 63;
  const int nt   = blockIdx.x >> 6;
  const int m0   = mt * 256, n0 = nt * 128;
  const int w    = tid >> 6, lane = tid & 63;
  const int r16  = lane & 15, kg = lane >> 4;

  floatx4 acc[4][8];
#pragma unroll
  for (int i = 0; i < 4; ++i)
#pragma unroll
    for (int j = 0; j < 8; ++j) acc[i][j] = floatx4{0.f, 0.f, 0.f, 0.f};

  // stage kb into Bs[buf]: 8KB contiguous fragment block of cbF
  auto stage = [&](int kb, int buf) {
    const unsigned short* src = cbF + (((size_t)(kb * 512 + nt * 8)) << 9);
#pragma unroll
    for (int i = 0; i < 2; ++i)
      gload_lds16(src + (((i * 256 + tid)) << 3),
                  &Bs[buf][(i * 256 + w * 64) << 3]);
  };
  // A fragment loads for one kb (4 x 16B coalesced global)
  const int rtw = mt * 16 + w * 4;
  auto loadA = [&](int kb, bhalf8* af) {
#pragma unroll
    for (int mi = 0; mi < 4; ++mi)
      af[mi] = *reinterpret_cast<const bhalf8*>(
          &zF[((size_t)((kb * 1024 + rtw + mi) * 64 + lane)) << 3]);
  };

  bhalf8 afc[4], afn[4];
  stage(0, 0);
  loadA(0, afc);
  __syncthreads();

#pragma unroll
  for (int kb = 0; kb < 8; ++kb) {
    const int cur = kb & 1;
    if (kb < 7) {
      stage(kb + 1, cur ^ 1);
      loadA(kb + 1, afn);
    }
    bhalf8 bf[8];
#pragma unroll
    for (int ni = 0; ni < 8; ++ni)
      bf[ni] = *reinterpret_cast<const bhalf8*>(&Bs[cur][(ni * 64 + lane) << 3]);
#pragma unroll
    for (int mi = 0; mi < 4; ++mi)
#pragma unroll
      for (int ni = 0; ni < 8; ++ni)
        acc[mi][ni] = __builtin_amdgcn_mfma_f32_16x16x32_bf16(
            afc[mi], bf[ni], acc[mi][ni], 0, 0, 0);
    __syncthreads();   // drains vmcnt (next stage + afn) and lgkm
#pragma unroll
    for (int mi = 0; mi < 4; ++mi) afc[mi] = afn[mi];
  }

  // C frag mapping (guide-verified): col = lane&15, row = (lane>>4)*4 + reg.
  if (PHASE == 0) {
#pragma unroll
    for (int mi = 0; mi < 4; ++mi)
#pragma unroll
      for (int reg = 0; reg < 4; ++reg) {
        float v = acc[mi][0][reg];
#pragma unroll
        for (int ni = 1; ni < 8; ++ni) v = fmaxf(v, acc[mi][ni][reg]);
#pragma unroll
        for (int off = 1; off < 16; off <<= 1) v = fmaxf(v, __shfl_xor(v, off));
        if (r16 == 0)
          rowmaxp[(size_t)nt * kRows + m0 + w * 64 + mi * 16 + kg * 4 + reg] = v;
      }
  } else {
#pragma unroll
    for (int mi = 0; mi < 4; ++mi)
#pragma unroll
      for (int reg = 0; reg < 4; ++reg) {
        const int row = m0 + w * 64 + mi * 16 + kg * 4 + reg;
        const float t = rowmax[row] - kMargin;
#pragma unroll
        for (int ni = 0; ni < 8; ++ni) {
          if (acc[mi][ni][reg] > t) {
            const unsigned slot = atomicAdd(cnt, 1u);
            if (slot < kCap)
              list[slot] = ((u64)(unsigned)row << 32) |
                           (unsigned)(n0 + ni * 16 + r16);
          }
        }
      }
  }
}

// rowmax[m] = max over 64 N-tiles.
__global__ __launch_bounds__(256) void vq_rmax(const float* __restrict__ rowmaxp,
                                               float* __restrict__ rowmax) {
  const int m = blockIdx.x * 256 + threadIdx.x;
  float v = rowmaxp[m];
  for (int s = 1; s < kNT; ++s) v = fmaxf(v, rowmaxp[(size_t)s * kRows + m]);
  rowmax[m] = v;
}

// Exact f32 rescore (bit-identical to R2 numerics): sequential ascending-k
// fmaf chain, dv = fl32(s - 2*dot); lex-min (dv, idx) via u64 atomicMin.
__global__ __launch_bounds__(256) void vq_rescore(
    const float* __restrict__ z, const float* __restrict__ cb,
    const float* __restrict__ srow, const u64* __restrict__ list,
    const unsigned* __restrict__ cnt, u64* __restrict__ pack) {
  const unsigned total = min(*cnt, kCap);
  for (unsigned i = blockIdx.x * 256 + threadIdx.x; i < total;
       i += gridDim.x * 256) {
    const u64 e = list[i];
    const int m = (int)(e >> 32);
    const int code = (int)(e & 0xffffffffu);
    const int b = m >> 10, hw = m & 1023;
    const float* zr = z + ((size_t)b << 18) + hw;
    const float* er = cb + (size_t)code * kDim;
    float d = 0.f;
    for (int k = 0; k < kDim; ++k)
      d = fmaf(zr[(size_t)k << 10], er[k], d);
    const float dv = __fsub_rn(srow[m], 2.0f * d);
    const u64 p = ((u64)__float_as_uint(dv) << 32) | (unsigned)code;
    atomicMin(pack + m, p);
  }
}

// Gather z_q to [B,C,H,W], idx output, f64 loss partials.
__global__ __launch_bounds__(256) void vq_out2(
    const float* __restrict__ z, const float* __restrict__ cb,
    const u64* __restrict__ pack, float* __restrict__ out,
    double* __restrict__ bloss) {
  __shared__ double wsum[4];
  const int tid  = threadIdx.x;
  const int lane = tid & 63;
  const int wv   = tid >> 6;
  const int m    = blockIdx.x * 4 + wv;
  const int b    = m >> 10;
  const int hw   = m & 1023;
  const u64 p = pack[m];
  const int best = (p == ~0ull) ? 0 : (int)(p & 0x7fffffffu);
  const float* zr = z + ((size_t)b << 18) + hw;
  const float* e  = cb + (size_t)best * kDim;
  float* o0 = out + ((size_t)b << 18) + hw;
  double acc = 0;
#pragma unroll
  for (int j = 0; j < 4; ++j) {
    const int d = lane + j * 64;
    const float ev = e[d];
    const float zv = zr[(size_t)d << 10];
    o0[(size_t)d << 10] = ev;
    const double diff = (double)ev - (double)zv;
    acc += diff * diff;
  }
#pragma unroll
  for (int off = 32; off > 0; off >>= 1) acc += __shfl_xor(acc, off);
  if (lane == 0) {
    out[kOutIdx + m] = (float)best;
    wsum[wv] = acc;
  }
  __syncthreads();
  if (tid == 0) bloss[blockIdx.x] = wsum[0] + wsum[1] + wsum[2] + wsum[3];
}

__global__ __launch_bounds__(256) void vq_final(
    const double* __restrict__ bloss, float* __restrict__ out) {
  __shared__ double sm[256];
  double s = 0;
  for (int i = threadIdx.x; i < kRows / 4; i += 256) s += bloss[i];
  sm[threadIdx.x] = s;
  __syncthreads();
  for (int st = 128; st > 0; st >>= 1) {
    if (threadIdx.x < st) sm[threadIdx.x] += sm[threadIdx.x + st];
    __syncthreads();
  }
  if (threadIdx.x == 0)
    out[kOutLoss] = (float)(1.25 * sm[0] / (double)kOutZq);
}

// ---------------- fallback path (verbatim Round-2, proven) ----------------

__global__ __launch_bounds__(256) void vq_pass1s(
    const float* __restrict__ z, const float* __restrict__ cb,
    int* __restrict__ cand) {
  __shared__ __align__(16) float As[kDim * 64];
  __shared__ __align__(16) float Bs[32 * 64];
  __shared__ float Ss[64];
  const int tid = threadIdx.x;
  const int m0  = blockIdx.x * 64;
  {
    const int r  = tid & 63;
    const int d0 = tid >> 6;
    const int n  = m0 + r;
    const int b  = n >> 10;
    const int hw = n & 1023;
    const float* zp = z + ((size_t)b << 18) + hw;
    for (int j = 0; j < 64; ++j) {
      const int d = d0 + (j << 2);
      As[d * 64 + r] = zp[(size_t)d << 10];
    }
  }
  __syncthreads();
  if (tid < 64) {
    float r8[8];
#pragma unroll
    for (int j = 0; j < 8; ++j) {
      const float v = As[j * 64 + tid];
      r8[j] = __fmul_rn(v, v);
    }
    for (int d = 8; d < kDim; d += 8) {
#pragma unroll
      for (int j = 0; j < 8; ++j) {
        const float v = As[(d + j) * 64 + tid];
        r8[j] = __fadd_rn(r8[j], __fmul_rn(v, v));
      }
    }
    Ss[tid] = __fadd_rn(
        __fadd_rn(__fadd_rn(r8[0], r8[1]), __fadd_rn(r8[2], r8[3])),
        __fadd_rn(__fadd_rn(r8[4], r8[5]), __fadd_rn(r8[6], r8[7])));
  }
  __syncthreads();
  const int tx = tid & 15;
  const int ty = tid >> 4;
  float srw[4];
#pragma unroll
  for (int i = 0; i < 4; ++i) srw[i] = Ss[ty * 4 + i];
  float bd[4]; int bi[4];
#pragma unroll
  for (int i = 0; i < 4; ++i) { bd[i] = 3.4e38f; bi[i] = 0; }
  for (int n0 = 0; n0 < kCodes; n0 += 64) {
    float acc[4][4];
#pragma unroll
    for (int i = 0; i < 4; ++i)
#pragma unroll
      for (int j = 0; j < 4; ++j) acc[i][j] = 0.f;
    for (int kc = 0; kc < kDim / 32; ++kc) {
      __syncthreads();
#pragma unroll
      for (int rep = 0; rep < 2; ++rep) {
        const int s  = tid + rep * 256;
        const int c  = s >> 3;
        const int fo = (s & 7) << 2;
        const float4 v = *reinterpret_cast<const float4*>(
            &cb[(size_t)(n0 + c) * kDim + kc * 32 + fo]);
        Bs[(fo + 0) * 64 + c] = v.x;
        Bs[(fo + 1) * 64 + c] = v.y;
        Bs[(fo + 2) * 64 + c] = v.z;
        Bs[(fo + 3) * 64 + c] = v.w;
      }
      __syncthreads();
#pragma unroll
      for (int kk = 0; kk < 32; ++kk) {
        const float4 av = *reinterpret_cast<const float4*>(
            &As[(kc * 32 + kk) * 64 + ty * 4]);
        const float4 bv = *reinterpret_cast<const float4*>(
            &Bs[kk * 64 + tx * 4]);
        const float a[4] = {av.x, av.y, av.z, av.w};
        const float b[4] = {bv.x, bv.y, bv.z, bv.w};
#pragma unroll
        for (int i = 0; i < 4; ++i)
#pragma unroll
          for (int j = 0; j < 4; ++j) acc[i][j] = fmaf(a[i], b[j], acc[i][j]);
      }
    }
#pragma unroll
    for (int i = 0; i < 4; ++i)
#pragma unroll
      for (int j = 0; j < 4; ++j) {
        const float dv = __fsub_rn(srw[i], 2.0f * acc[i][j]);
        if (dv < bd[i]) { bd[i] = dv; bi[i] = n0 + tx * 4 + j; }
      }
  }
  __syncthreads();
  float2* merge = reinterpret_cast<float2*>(As);
#pragma unroll
  for (int i = 0; i < 4; ++i)
    merge[(ty * 4 + i) * 16 + tx] = make_float2(bd[i], __int_as_float(bi[i]));
  __syncthreads();
  if (tid < 64) {
    float best = 3.4e38f;
    int   besti = 0x7fffffff;
    for (int t = 0; t < 16; ++t) {
      const float2 mv = merge[tid * 16 + t];
      const int ii = __float_as_int(mv.y);
      if (mv.x < best || (mv.x == best && ii < besti)) { best = mv.x; besti = ii; }
    }
    cand[m0 + tid] = besti;
  }
}

__global__ __launch_bounds__(256) void vq_outs(
    const float* __restrict__ z, const float* __restrict__ cb,
    const int* __restrict__ cand, float* __restrict__ out,
    double* __restrict__ bloss) {
  __shared__ double wsum[4];
  const int tid  = threadIdx.x;
  const int lane = tid & 63;
  const int wv   = tid >> 6;
  const int m    = blockIdx.x * 4 + wv;
  const int b    = m >> 10;
  const int hw   = m & 1023;
  const float* zr = z + ((size_t)b << 18) + hw;
  const int best = cand[m];
  const float* e = cb + (size_t)best * kDim;
  float* o0 = out + ((size_t)b << 18) + hw;
  double acc = 0;
#pragma unroll
  for (int j = 0; j < 4; ++j) {
    const int d = lane + j * 64;
    const float ev = e[d];
    const float zv = zr[(size_t)d << 10];
    o0[(size_t)d << 10] = ev;
    const double diff = (double)ev - (double)zv;
    acc += diff * diff;
  }
#pragma unroll
  for (int off = 32; off > 0; off >>= 1) acc += __shfl_xor(acc, off);
  if (lane == 0) {
    out[kOutIdx + m] = (float)best;
    wsum[wv] = acc;
  }
  __syncthreads();
  if (tid == 0) bloss[blockIdx.x] = wsum[0] + wsum[1] + wsum[2] + wsum[3];
}

extern "C" void kernel_launch(void* const* d_in, const int* in_sizes, int n_in,
                              void* d_out, int out_size, void* d_ws, size_t ws_size,
                              hipStream_t stream) {
  const float* z  = (const float*)d_in[0];
  const float* cb = (const float*)d_in[1];
  float* out = (float*)d_out;

  if (ws_size >= kWsNeed) {
    unsigned short* zF  = (unsigned short*)((char*)d_ws + kOffZf);
    unsigned short* cbF = (unsigned short*)((char*)d_ws + kOffCbf);
    float* srow    = (float*)((char*)d_ws + kOffSrow);
    float* rowmax  = (float*)((char*)d_ws + kOffRmax);
    float* rowmaxp = (float*)((char*)d_ws + kOffRmaxP);
    u64*   pack    = (u64*)((char*)d_ws + kOffPack);
    u64*   list    = (u64*)((char*)d_ws + kOffList);
    unsigned* cnt  = (unsigned*)((char*)d_ws + kOffCnt);
    double* bloss  = (double*)((char*)d_ws + kOffBloss);

    vq_convz  <<<2048, 256, 0, stream>>>(z, zF);
    vq_convcb <<<1024, 256, 0, stream>>>(cb, cbF);
    vq_rows   <<<kRows / 256, 256, 0, stream>>>(z, srow, pack, cnt);
    vq_gemm<0><<<4096, 256, 0, stream>>>(zF, cbF, rowmax, rowmaxp, list, cnt);
    vq_rmax   <<<kRows / 256, 256, 0, stream>>>(rowmaxp, rowmax);
    vq_gemm<1><<<4096, 256, 0, stream>>>(zF, cbF, rowmax, rowmaxp, list, cnt);
    vq_rescore<<<256, 256, 0, stream>>>(z, cb, srow, list, cnt, pack);
    vq_out2   <<<kRows / 4, 256, 0, stream>>>(z, cb, pack, out, bloss);
    vq_final  <<<1, 256, 0, stream>>>(bloss, out);
  } else {
    int*    cand  = (int*)d_ws;
    double* bloss = (double*)((char*)d_ws + kRows * sizeof(int));
    vq_pass1s<<<kRows / 64, 256, 0, stream>>>(z, cb, cand);
    vq_outs  <<<kRows / 4,  256, 0, stream>>>(z, cb, cand, out, bloss);
    vq_final <<<1, 256, 0, stream>>>(bloss, out);
  }
}